// Round 3
// baseline (35.914 us; speedup 1.0000x reference)
//
#include <hip/hip_runtime.h>

// Problem constants (match the reference file).
#define IN_F   4096
#define OUT_F  4094   // IN_FEATURES - 2
#define BATCH_ 4096
#define WCOLS  3      // min(3, OUT_F)

// clang native vector types — valid for __builtin_nontemporal_{load,store}
typedef float f32x4 __attribute__((ext_vector_type(4)));
typedef float f32x2 __attribute__((ext_vector_type(2)));

// ---------------------------------------------------------------------------
// Fused kernel: one 256-thread block per output row b.
//   out[b, 0:3]    = dot(input[b,:], weight[0:3,:].T) + IN_F * bias[0:3]
//   out[b, 3:4094] = 0
// Phase A: partial dots (float4 loads; weight rows L2-resident, 48 KB).
// Phase B: zero the whole row with float2 nontemporal stores (row base is
//          8B-aligned: 4094*4 = 16376 ≡ 8 mod 16, so float4 is unsafe).
// Phase C: wave shfl-reduce -> LDS -> threads 0..2 overwrite live columns.
//          The reduction __syncthreads orders B before C.
// ---------------------------------------------------------------------------
__global__ __launch_bounds__(256) void fused_row_kernel(const float* __restrict__ in,
                                                        const float* __restrict__ w,
                                                        const float* __restrict__ bias,
                                                        float* __restrict__ out) {
    const int b   = blockIdx.x;
    const int tid = threadIdx.x;

    const f32x4* __restrict__ row = (const f32x4*)(in + (long)b * IN_F);
    const f32x4* __restrict__ w0  = (const f32x4*)(w);
    const f32x4* __restrict__ w1  = (const f32x4*)(w + IN_F);
    const f32x4* __restrict__ w2  = (const f32x4*)(w + 2 * IN_F);

    float s0 = 0.f, s1 = 0.f, s2 = 0.f;

    // IN_F/4 = 1024 float4 per row; 256 threads -> 4 iterations each.
    #pragma unroll 4
    for (int i = tid; i < IN_F / 4; i += 256) {
        f32x4 x = __builtin_nontemporal_load(&row[i]);   // streamed once
        f32x4 a = w0[i];
        f32x4 c = w1[i];
        f32x4 d = w2[i];
        s0 = fmaf(x.x, a.x, fmaf(x.y, a.y, fmaf(x.z, a.z, fmaf(x.w, a.w, s0))));
        s1 = fmaf(x.x, c.x, fmaf(x.y, c.y, fmaf(x.z, c.z, fmaf(x.w, c.w, s1))));
        s2 = fmaf(x.x, d.x, fmaf(x.y, d.y, fmaf(x.z, d.z, fmaf(x.w, d.w, s2))));
    }

    // Phase B: zero this row. OUT_F/2 = 2047 float2 covers floats 0..4093.
    f32x2* __restrict__ orow = (f32x2*)(out + (long)b * OUT_F);
    const f32x2 z2 = {0.f, 0.f};
    #pragma unroll
    for (int i = tid; i < OUT_F / 2; i += 256) {
        __builtin_nontemporal_store(z2, &orow[i]);
    }

    // Phase C: reduce. Wave = 64 lanes on gfx950.
    #pragma unroll
    for (int off = 32; off > 0; off >>= 1) {
        s0 += __shfl_down(s0, off);
        s1 += __shfl_down(s1, off);
        s2 += __shfl_down(s2, off);
    }

    __shared__ float red[4][WCOLS];
    const int wave = tid >> 6;
    const int lane = tid & 63;
    if (lane == 0) {
        red[wave][0] = s0;
        red[wave][1] = s1;
        red[wave][2] = s2;
    }
    __syncthreads();   // also orders Phase B stores before Phase C writes

    if (tid < WCOLS) {
        float t = red[0][tid] + red[1][tid] + red[2][tid] + red[3][tid];
        out[(long)b * OUT_F + tid] = t + (float)IN_F * bias[tid];
    }
}

extern "C" void kernel_launch(void* const* d_in, const int* in_sizes, int n_in,
                              void* d_out, int out_size, void* d_ws, size_t ws_size,
                              hipStream_t stream) {
    const float* in   = (const float*)d_in[0];   // (4096, 4096) fp32
    const float* w    = (const float*)d_in[1];   // (4094, 4096) fp32
    const float* bias = (const float*)d_in[2];   // (4094,) fp32
    float* out = (float*)d_out;                  // (4096, 4094) fp32

    fused_row_kernel<<<BATCH_, 256, 0, stream>>>(in, w, bias, out);
}